// Round 6
// baseline (481.958 us; speedup 1.0000x reference)
//
#include <hip/hip_runtime.h>
#include <math.h>

// SatelliteEvolveGCN, collapsed:
//   - only the LAST timestep's gcn_conv matters (scan discards carried h)
//   - mean over nodes of segment_sum == global sum over all messages / N
// R1: pack per-node {xw*dinv, dinv} as float4 -> 2 gathers/edge (was 5);
//     fuse evolve into degree kernel, final into edge kernel; 1 memset.
// R4: separate dinv[] array for dst gathers (16 vals/line vs 4),
//     nontemporal index loads (don't evict gather tables from L2),
//     2048-block grids for degree/edge latency hiding.
// R6: nontemporal loads via Clang ext_vector_type (HIP int4 class rejected
//     by __builtin_nontemporal_load).
// ws layout: [0,24) gsum doubles, [64,68) done-counter, [128,400128) deg ints,
//            [400128,400164) wfin, [400192,2000192) v4, [2000192,2400192) dinv.
// memset [0,400128) only.

namespace {

constexpr int T_STEPS  = 20;
constexpr int N_NODES  = 100000;
constexpr int E_EDGES  = 1600000;
constexpr int EDGE_BLOCKS = 2048;

typedef int iv4 __attribute__((ext_vector_type(4)));   // nontemporal-compatible

__device__ __forceinline__ float sigmoidf(float v) {
  return 1.0f / (1.0f + expf(-v));
}

// ---- degree histogram over dst; block 0 lanes 0..8 also evolve W (20 GRU steps) ----
__global__ __launch_bounds__(256) void degree_evolve_kernel(
    const int* __restrict__ dst, int* __restrict__ deg, int E,
    const float* __restrict__ W0, const float* __restrict__ Wi,
    const float* __restrict__ Wh, const float* __restrict__ bi,
    const float* __restrict__ bh, float* __restrict__ wfin) {
  if (blockIdx.x == 0 && threadIdx.x < 9) {
    const int lane = threadIdx.x;
    const int i = lane / 3, c = lane % 3;
    float wiR[3], wiZ[3], wiN[3], whR[3], whZ[3], whN[3];
#pragma unroll
    for (int k = 0; k < 3; ++k) {
      wiR[k] = Wi[(0 + c) * 3 + k];
      wiZ[k] = Wi[(3 + c) * 3 + k];
      wiN[k] = Wi[(6 + c) * 3 + k];
      whR[k] = Wh[(0 + c) * 3 + k];
      whZ[k] = Wh[(3 + c) * 3 + k];
      whN[k] = Wh[(6 + c) * 3 + k];
    }
    const float biR = bi[c], biZ = bi[3 + c], biN = bi[6 + c];
    const float bhR = bh[c], bhZ = bh[3 + c], bhN = bh[6 + c];
    float w = W0[lane];
    for (int t = 0; t < T_STEPS; ++t) {
      const float w0 = __shfl(w, 3 * i + 0, 64);   // row i of current w
      const float w1 = __shfl(w, 3 * i + 1, 64);
      const float w2 = __shfl(w, 3 * i + 2, 64);
      const float giR = biR + w0 * wiR[0] + w1 * wiR[1] + w2 * wiR[2];
      const float giZ = biZ + w0 * wiZ[0] + w1 * wiZ[1] + w2 * wiZ[2];
      const float giN = biN + w0 * wiN[0] + w1 * wiN[1] + w2 * wiN[2];
      const float ghR = bhR + w0 * whR[0] + w1 * whR[1] + w2 * whR[2];
      const float ghZ = bhZ + w0 * whZ[0] + w1 * whZ[1] + w2 * whZ[2];
      const float ghN = bhN + w0 * whN[0] + w1 * whN[1] + w2 * whN[2];
      const float r = sigmoidf(giR + ghR);
      const float z = sigmoidf(giZ + ghZ);
      const float n = tanhf(giN + r * ghN);
      w = (1.0f - z) * n + z * w;
    }
    wfin[lane] = w;
  }
  const int tid = blockIdx.x * blockDim.x + threadIdx.x;
  const int stride = gridDim.x * blockDim.x;
  const int E4 = E >> 2;
  const iv4* d4 = reinterpret_cast<const iv4*>(dst);
  for (int e = tid; e < E4; e += stride) {
    const iv4 v = __builtin_nontemporal_load(&d4[e]);   // streamed once
    atomicAdd(&deg[v.x], 1);
    atomicAdd(&deg[v.y], 1);
    atomicAdd(&deg[v.z], 1);
    atomicAdd(&deg[v.w], 1);
  }
  for (int e = (E4 << 2) + tid; e < E; e += stride) atomicAdd(&deg[dst[e]], 1);
}

__device__ __forceinline__ void block_reduce3(float& a0, float& a1, float& a2) {
#pragma unroll
  for (int off = 32; off > 0; off >>= 1) {
    a0 += __shfl_down(a0, off, 64);
    a1 += __shfl_down(a1, off, 64);
    a2 += __shfl_down(a2, off, 64);
  }
  __shared__ float r0[4], r1[4], r2[4];   // up to 4 waves (blockDim 256)
  const int wid = threadIdx.x >> 6;
  if ((threadIdx.x & 63) == 0) { r0[wid] = a0; r1[wid] = a1; r2[wid] = a2; }
  __syncthreads();
  if (threadIdx.x == 0) {
    a0 = a1 = a2 = 0.f;
    const int nw = blockDim.x >> 6;
    for (int w = 0; w < nw; ++w) { a0 += r0[w]; a1 += r1[w]; a2 += r2[w]; }
  }
}

// ---- per-node: di = rsqrt(deg+1); v4[i]={xw*di,di}; dinv[i]=di; self-loop sum ----
__global__ __launch_bounds__(256) void node_kernel(const float* __restrict__ x,
                                                   const int* __restrict__ deg,
                                                   float4* __restrict__ v4,
                                                   float* __restrict__ dinv,
                                                   const float* __restrict__ wfin,
                                                   double* __restrict__ gsum, int N) {
  __shared__ float W[9];
  if (threadIdx.x < 9) W[threadIdx.x] = wfin[threadIdx.x];
  __syncthreads();
  float a0 = 0.f, a1 = 0.f, a2 = 0.f;
  const int stride = gridDim.x * blockDim.x;
  for (int idx = blockIdx.x * blockDim.x + threadIdx.x; idx < N; idx += stride) {
    const float x0 = x[3 * idx + 0];
    const float x1 = x[3 * idx + 1];
    const float x2 = x[3 * idx + 2];
    const int dg = deg[idx] + 1;                   // +1 self loop
    const float di = 1.0f / sqrtf((float)dg);
    const float s0 = (x0 * W[0] + x1 * W[3] + x2 * W[6]) * di;   // (x@W)*di
    const float s1 = (x0 * W[1] + x1 * W[4] + x2 * W[7]) * di;
    const float s2 = (x0 * W[2] + x1 * W[5] + x2 * W[8]) * di;
    v4[idx] = make_float4(s0, s1, s2, di);
    dinv[idx] = di;
    a0 += s0 * di; a1 += s1 * di; a2 += s2 * di;   // self-loop: xw*di^2
  }
  block_reduce3(a0, a1, a2);
  if (threadIdx.x == 0) {
    atomicAdd(&gsum[0], (double)a0);
    atomicAdd(&gsum[1], (double)a1);
    atomicAdd(&gsum[2], (double)a2);
  }
}

// ---- per-edge: sum_e v4[src].xyz * dinv[dst] ; last block finalizes output ----
__global__ __launch_bounds__(256) void edge_final_kernel(
    const int* __restrict__ src, const int* __restrict__ dst,
    const float4* __restrict__ v4, const float* __restrict__ dinv,
    double* __restrict__ gsum, unsigned* __restrict__ counter,
    const float* __restrict__ conv_bias, const float* __restrict__ linW,
    const float* __restrict__ linb, float* __restrict__ out, int E, int N) {
  float a0 = 0.f, a1 = 0.f, a2 = 0.f;
  const int tid = blockIdx.x * blockDim.x + threadIdx.x;
  const int stride = gridDim.x * blockDim.x;
  const int E4 = E >> 2;
  const iv4* s4 = reinterpret_cast<const iv4*>(src);
  const iv4* d4 = reinterpret_cast<const iv4*>(dst);
  for (int e = tid; e < E4; e += stride) {
    const iv4 sv = __builtin_nontemporal_load(&s4[e]);   // streamed once
    const iv4 dv = __builtin_nontemporal_load(&d4[e]);
    {
      const float4 a = v4[sv.x]; const float b = dinv[dv.x];
      a0 += a.x * b; a1 += a.y * b; a2 += a.z * b;
    }
    {
      const float4 a = v4[sv.y]; const float b = dinv[dv.y];
      a0 += a.x * b; a1 += a.y * b; a2 += a.z * b;
    }
    {
      const float4 a = v4[sv.z]; const float b = dinv[dv.z];
      a0 += a.x * b; a1 += a.y * b; a2 += a.z * b;
    }
    {
      const float4 a = v4[sv.w]; const float b = dinv[dv.w];
      a0 += a.x * b; a1 += a.y * b; a2 += a.z * b;
    }
  }
  for (int e = (E4 << 2) + tid; e < E; e += stride) {
    const float4 a = v4[src[e]]; const float b = dinv[dst[e]];
    a0 += a.x * b; a1 += a.y * b; a2 += a.z * b;
  }
  block_reduce3(a0, a1, a2);
  if (threadIdx.x == 0) {
    atomicAdd(&gsum[0], (double)a0);
    atomicAdd(&gsum[1], (double)a1);
    atomicAdd(&gsum[2], (double)a2);
    __threadfence();                                // publish before counting
    const unsigned done = atomicAdd(counter, 1u);
    if (done == gridDim.x - 1) {                    // last block: finalize
      const double g0 = atomicAdd(&gsum[0], 0.0);   // coherent read
      const double g1 = atomicAdd(&gsum[1], 0.0);
      const double g2 = atomicAdd(&gsum[2], 0.0);
      const float e0 = (float)(g0 / (double)N) + conv_bias[0];
      const float e1 = (float)(g1 / (double)N) + conv_bias[1];
      const float e2 = (float)(g2 / (double)N) + conv_bias[2];
      out[0] = e0 * linW[0] + e1 * linW[1] + e2 * linW[2] + linb[0];
      out[1] = e0 * linW[3] + e1 * linW[4] + e2 * linW[5] + linb[1];
    }
  }
}

}  // namespace

extern "C" void kernel_launch(void* const* d_in, const int* in_sizes, int n_in,
                              void* d_out, int out_size, void* d_ws, size_t ws_size,
                              hipStream_t stream) {
  const float* x  = (const float*)d_in[0];   // [T,N,3]
  const int*   ei = (const int*)  d_in[1];   // [T,2,E]
  const float* W0 = (const float*)d_in[2];   // [3,3]
  const float* Wi = (const float*)d_in[3];   // [9,3]
  const float* Wh = (const float*)d_in[4];   // [9,3]
  const float* bi = (const float*)d_in[5];   // [9]
  const float* bh = (const float*)d_in[6];   // [9]
  const float* cb = (const float*)d_in[7];   // [3]
  const float* lW = (const float*)d_in[8];   // [2,3]
  const float* lb = (const float*)d_in[9];   // [2]
  float* out = (float*)d_out;

  char* ws = (char*)d_ws;
  double*   gsum    = (double*)ws;                      // [0,24)
  unsigned* counter = (unsigned*)(ws + 64);             // [64,68)
  int*      deg     = (int*)(ws + 128);                 // [128, 400128)
  float*    wfin    = (float*)(ws + 400128);            // 36 B
  float4*   v4      = (float4*)(ws + 400192);           // [400192, 2000192)
  float*    dinv    = (float*)(ws + 2000192);           // [2000192, 2400192)

  const int tlast = T_STEPS - 1;
  const float* x_last = x + (size_t)tlast * N_NODES * 3;
  const int*   src    = ei + (size_t)tlast * 2 * E_EDGES;
  const int*   dst    = src + E_EDGES;

  // zero gsum + counter + deg in one fill
  (void)hipMemsetAsync(ws, 0, 400128, stream);

  degree_evolve_kernel<<<2048, 256, 0, stream>>>(dst, deg, E_EDGES,
                                                 W0, Wi, Wh, bi, bh, wfin);
  node_kernel<<<512, 256, 0, stream>>>(x_last, deg, v4, dinv, wfin, gsum, N_NODES);
  edge_final_kernel<<<EDGE_BLOCKS, 256, 0, stream>>>(src, dst, v4, dinv, gsum,
                                                     counter, cb, lW, lb, out,
                                                     E_EDGES, N_NODES);
}

// Round 11
// 442.032 us; speedup vs baseline: 1.0903x; 1.0903x over previous
//
#include <hip/hip_runtime.h>
#include <math.h>

// SatelliteEvolveGCN, collapsed:
//   - only the LAST timestep's gcn_conv matters (scan discards carried h)
//   - mean over nodes of segment_sum == global sum over all messages / N
// R1: pack per-node {xw*dinv, dinv} as float4 -> 2 gathers/edge (was 5);
//     fuse evolve into degree kernel, final into edge kernel; 1 memset.
// R4/R6: dinv split + nt loads + 2048 grids -> REGRESSED (+36us). Suspect:
//     doubled same-address f64 atomics (cross-XCD line migration) from the
//     2048-block tail, and unproven nt loads.
// R7: revert to R3 grids (1024/512/1024) and plain int4 loads; KEEP dinv
//     split (dst gathers hit 16 vals/cacheline vs 4 - mechanism-sound).
// R8-R11: identical resubmits (R7-R10 never ran — GPU acquisition timeouts).
// ws layout: [0,24) gsum doubles, [64,68) done-counter, [128,400128) deg ints,
//            [400128,400164) wfin, [400192,2000192) v4, [2000192,2400192) dinv.
// memset [0,400128) only.

namespace {

constexpr int T_STEPS  = 20;
constexpr int N_NODES  = 100000;
constexpr int E_EDGES  = 1600000;
constexpr int EDGE_BLOCKS = 1024;

__device__ __forceinline__ float sigmoidf(float v) {
  return 1.0f / (1.0f + expf(-v));
}

// ---- degree histogram over dst; block 0 lanes 0..8 also evolve W (20 GRU steps) ----
__global__ __launch_bounds__(256) void degree_evolve_kernel(
    const int* __restrict__ dst, int* __restrict__ deg, int E,
    const float* __restrict__ W0, const float* __restrict__ Wi,
    const float* __restrict__ Wh, const float* __restrict__ bi,
    const float* __restrict__ bh, float* __restrict__ wfin) {
  if (blockIdx.x == 0 && threadIdx.x < 9) {
    const int lane = threadIdx.x;
    const int i = lane / 3, c = lane % 3;
    float wiR[3], wiZ[3], wiN[3], whR[3], whZ[3], whN[3];
#pragma unroll
    for (int k = 0; k < 3; ++k) {
      wiR[k] = Wi[(0 + c) * 3 + k];
      wiZ[k] = Wi[(3 + c) * 3 + k];
      wiN[k] = Wi[(6 + c) * 3 + k];
      whR[k] = Wh[(0 + c) * 3 + k];
      whZ[k] = Wh[(3 + c) * 3 + k];
      whN[k] = Wh[(6 + c) * 3 + k];
    }
    const float biR = bi[c], biZ = bi[3 + c], biN = bi[6 + c];
    const float bhR = bh[c], bhZ = bh[3 + c], bhN = bh[6 + c];
    float w = W0[lane];
    for (int t = 0; t < T_STEPS; ++t) {
      const float w0 = __shfl(w, 3 * i + 0, 64);   // row i of current w
      const float w1 = __shfl(w, 3 * i + 1, 64);
      const float w2 = __shfl(w, 3 * i + 2, 64);
      const float giR = biR + w0 * wiR[0] + w1 * wiR[1] + w2 * wiR[2];
      const float giZ = biZ + w0 * wiZ[0] + w1 * wiZ[1] + w2 * wiZ[2];
      const float giN = biN + w0 * wiN[0] + w1 * wiN[1] + w2 * wiN[2];
      const float ghR = bhR + w0 * whR[0] + w1 * whR[1] + w2 * whR[2];
      const float ghZ = bhZ + w0 * whZ[0] + w1 * whZ[1] + w2 * whZ[2];
      const float ghN = bhN + w0 * whN[0] + w1 * whN[1] + w2 * whN[2];
      const float r = sigmoidf(giR + ghR);
      const float z = sigmoidf(giZ + ghZ);
      const float n = tanhf(giN + r * ghN);
      w = (1.0f - z) * n + z * w;
    }
    wfin[lane] = w;
  }
  const int tid = blockIdx.x * blockDim.x + threadIdx.x;
  const int stride = gridDim.x * blockDim.x;
  const int E4 = E >> 2;
  const int4* d4 = reinterpret_cast<const int4*>(dst);
  for (int e = tid; e < E4; e += stride) {
    const int4 v = d4[e];
    atomicAdd(&deg[v.x], 1);
    atomicAdd(&deg[v.y], 1);
    atomicAdd(&deg[v.z], 1);
    atomicAdd(&deg[v.w], 1);
  }
  for (int e = (E4 << 2) + tid; e < E; e += stride) atomicAdd(&deg[dst[e]], 1);
}

__device__ __forceinline__ void block_reduce3(float& a0, float& a1, float& a2) {
#pragma unroll
  for (int off = 32; off > 0; off >>= 1) {
    a0 += __shfl_down(a0, off, 64);
    a1 += __shfl_down(a1, off, 64);
    a2 += __shfl_down(a2, off, 64);
  }
  __shared__ float r0[4], r1[4], r2[4];   // up to 4 waves (blockDim 256)
  const int wid = threadIdx.x >> 6;
  if ((threadIdx.x & 63) == 0) { r0[wid] = a0; r1[wid] = a1; r2[wid] = a2; }
  __syncthreads();
  if (threadIdx.x == 0) {
    a0 = a1 = a2 = 0.f;
    const int nw = blockDim.x >> 6;
    for (int w = 0; w < nw; ++w) { a0 += r0[w]; a1 += r1[w]; a2 += r2[w]; }
  }
}

// ---- per-node: di = rsqrt(deg+1); v4[i]={xw*di,di}; dinv[i]=di; self-loop sum ----
__global__ __launch_bounds__(256) void node_kernel(const float* __restrict__ x,
                                                   const int* __restrict__ deg,
                                                   float4* __restrict__ v4,
                                                   float* __restrict__ dinv,
                                                   const float* __restrict__ wfin,
                                                   double* __restrict__ gsum, int N) {
  __shared__ float W[9];
  if (threadIdx.x < 9) W[threadIdx.x] = wfin[threadIdx.x];
  __syncthreads();
  float a0 = 0.f, a1 = 0.f, a2 = 0.f;
  const int stride = gridDim.x * blockDim.x;
  for (int idx = blockIdx.x * blockDim.x + threadIdx.x; idx < N; idx += stride) {
    const float x0 = x[3 * idx + 0];
    const float x1 = x[3 * idx + 1];
    const float x2 = x[3 * idx + 2];
    const int dg = deg[idx] + 1;                   // +1 self loop
    const float di = 1.0f / sqrtf((float)dg);
    const float s0 = (x0 * W[0] + x1 * W[3] + x2 * W[6]) * di;   // (x@W)*di
    const float s1 = (x0 * W[1] + x1 * W[4] + x2 * W[7]) * di;
    const float s2 = (x0 * W[2] + x1 * W[5] + x2 * W[8]) * di;
    v4[idx] = make_float4(s0, s1, s2, di);
    dinv[idx] = di;
    a0 += s0 * di; a1 += s1 * di; a2 += s2 * di;   // self-loop: xw*di^2
  }
  block_reduce3(a0, a1, a2);
  if (threadIdx.x == 0) {
    atomicAdd(&gsum[0], (double)a0);
    atomicAdd(&gsum[1], (double)a1);
    atomicAdd(&gsum[2], (double)a2);
  }
}

// ---- per-edge: sum_e v4[src].xyz * dinv[dst] ; last block finalizes output ----
__global__ __launch_bounds__(256) void edge_final_kernel(
    const int* __restrict__ src, const int* __restrict__ dst,
    const float4* __restrict__ v4, const float* __restrict__ dinv,
    double* __restrict__ gsum, unsigned* __restrict__ counter,
    const float* __restrict__ conv_bias, const float* __restrict__ linW,
    const float* __restrict__ linb, float* __restrict__ out, int E, int N) {
  float a0 = 0.f, a1 = 0.f, a2 = 0.f;
  const int tid = blockIdx.x * blockDim.x + threadIdx.x;
  const int stride = gridDim.x * blockDim.x;
  const int E4 = E >> 2;
  const int4* s4 = reinterpret_cast<const int4*>(src);
  const int4* d4 = reinterpret_cast<const int4*>(dst);
  for (int e = tid; e < E4; e += stride) {
    const int4 sv = s4[e];
    const int4 dv = d4[e];
    {
      const float4 a = v4[sv.x]; const float b = dinv[dv.x];
      a0 += a.x * b; a1 += a.y * b; a2 += a.z * b;
    }
    {
      const float4 a = v4[sv.y]; const float b = dinv[dv.y];
      a0 += a.x * b; a1 += a.y * b; a2 += a.z * b;
    }
    {
      const float4 a = v4[sv.z]; const float b = dinv[dv.z];
      a0 += a.x * b; a1 += a.y * b; a2 += a.z * b;
    }
    {
      const float4 a = v4[sv.w]; const float b = dinv[dv.w];
      a0 += a.x * b; a1 += a.y * b; a2 += a.z * b;
    }
  }
  for (int e = (E4 << 2) + tid; e < E; e += stride) {
    const float4 a = v4[src[e]]; const float b = dinv[dst[e]];
    a0 += a.x * b; a1 += a.y * b; a2 += a.z * b;
  }
  block_reduce3(a0, a1, a2);
  if (threadIdx.x == 0) {
    atomicAdd(&gsum[0], (double)a0);
    atomicAdd(&gsum[1], (double)a1);
    atomicAdd(&gsum[2], (double)a2);
    __threadfence();                                // publish before counting
    const unsigned done = atomicAdd(counter, 1u);
    if (done == gridDim.x - 1) {                    // last block: finalize
      const double g0 = atomicAdd(&gsum[0], 0.0);   // coherent read
      const double g1 = atomicAdd(&gsum[1], 0.0);
      const double g2 = atomicAdd(&gsum[2], 0.0);
      const float e0 = (float)(g0 / (double)N) + conv_bias[0];
      const float e1 = (float)(g1 / (double)N) + conv_bias[1];
      const float e2 = (float)(g2 / (double)N) + conv_bias[2];
      out[0] = e0 * linW[0] + e1 * linW[1] + e2 * linW[2] + linb[0];
      out[1] = e0 * linW[3] + e1 * linW[4] + e2 * linW[5] + linb[1];
    }
  }
}

}  // namespace

extern "C" void kernel_launch(void* const* d_in, const int* in_sizes, int n_in,
                              void* d_out, int out_size, void* d_ws, size_t ws_size,
                              hipStream_t stream) {
  const float* x  = (const float*)d_in[0];   // [T,N,3]
  const int*   ei = (const int*)  d_in[1];   // [T,2,E]
  const float* W0 = (const float*)d_in[2];   // [3,3]
  const float* Wi = (const float*)d_in[3];   // [9,3]
  const float* Wh = (const float*)d_in[4];   // [9,3]
  const float* bi = (const float*)d_in[5];   // [9]
  const float* bh = (const float*)d_in[6];   // [9]
  const float* cb = (const float*)d_in[7];   // [3]
  const float* lW = (const float*)d_in[8];   // [2,3]
  const float* lb = (const float*)d_in[9];   // [2]
  float* out = (float*)d_out;

  char* ws = (char*)d_ws;
  double*   gsum    = (double*)ws;                      // [0,24)
  unsigned* counter = (unsigned*)(ws + 64);             // [64,68)
  int*      deg     = (int*)(ws + 128);                 // [128, 400128)
  float*    wfin    = (float*)(ws + 400128);            // 36 B
  float4*   v4      = (float4*)(ws + 400192);           // [400192, 2000192)
  float*    dinv    = (float*)(ws + 2000192);           // [2000192, 2400192)

  const int tlast = T_STEPS - 1;
  const float* x_last = x + (size_t)tlast * N_NODES * 3;
  const int*   src    = ei + (size_t)tlast * 2 * E_EDGES;
  const int*   dst    = src + E_EDGES;

  // zero gsum + counter + deg in one fill
  (void)hipMemsetAsync(ws, 0, 400128, stream);

  degree_evolve_kernel<<<1024, 256, 0, stream>>>(dst, deg, E_EDGES,
                                                 W0, Wi, Wh, bi, bh, wfin);
  node_kernel<<<512, 256, 0, stream>>>(x_last, deg, v4, dinv, wfin, gsum, N_NODES);
  edge_final_kernel<<<EDGE_BLOCKS, 256, 0, stream>>>(src, dst, v4, dinv, gsum,
                                                     counter, cb, lW, lb, out,
                                                     E_EDGES, N_NODES);
}